// Round 9
// baseline (466.102 us; speedup 1.0000x reference)
//
#include <hip/hip_runtime.h>
#include <cfloat>
#include <math.h>

#define NUM_EMB 8192
#define DIM 256
#define NROWS 32768
#define NSPLIT 4
#define CHUNKS 16   // 8192 / NSPLIT / 128

typedef float f32x4 __attribute__((ext_vector_type(4)));
typedef int   i32x4 __attribute__((ext_vector_type(4)));
typedef int   i32x8 __attribute__((ext_vector_type(8)));

#define GL2LDS(g, l) __builtin_amdgcn_global_load_lds( \
    (const __attribute__((address_space(1))) void*)(g), \
    (__attribute__((address_space(3))) void*)(l), 16, 0, 0)

// ---------------- prep: x -> fp8 ; codebook -> fp8(e*8192) + biased norms ; zero counts/ctr ----------------
__global__ __launch_bounds__(256) void vq_prep(const float* __restrict__ x,
                                               unsigned char* __restrict__ xq,
                                               const float* __restrict__ cb,
                                               unsigned char* __restrict__ cbq,
                                               float* __restrict__ cbn,
                                               unsigned int* __restrict__ counts,
                                               unsigned int* __restrict__ ctr) {
    int b = blockIdx.x;
    if (b < 4096) {
        int i = b * 256 + threadIdx.x;               // over 8-float groups
        float4 v0 = ((const float4*)x)[2 * i];
        float4 v1 = ((const float4*)x)[2 * i + 1];
        int p0 = __builtin_amdgcn_cvt_pk_fp8_f32(v0.x, v0.y, 0, false);
        p0     = __builtin_amdgcn_cvt_pk_fp8_f32(v0.z, v0.w, p0, true);
        int p1 = __builtin_amdgcn_cvt_pk_fp8_f32(v1.x, v1.y, 0, false);
        p1     = __builtin_amdgcn_cvt_pk_fp8_f32(v1.z, v1.w, p1, true);
        ((int2*)xq)[i] = make_int2(p0, p1);
    } else if (b < 6144) {
        int row  = (b - 4096) * 4 + (threadIdx.x >> 6);
        int lane = threadIdx.x & 63;
        float4 v = ((const float4*)(cb + (size_t)row * DIM))[lane];
        // store e*8192 in fp8 (range (-1,1)); scale folds out of the argmin
        int p = __builtin_amdgcn_cvt_pk_fp8_f32(v.x * 8192.f, v.y * 8192.f, 0, false);
        p     = __builtin_amdgcn_cvt_pk_fp8_f32(v.z * 8192.f, v.w * 8192.f, p, true);
        ((int*)cbq)[row * 64 + lane] = p;
        float s = v.x * v.x + v.y * v.y + v.z * v.z + v.w * v.w;
        #pragma unroll
        for (int off = 32; off > 0; off >>= 1) s += __shfl_down(s, off, 64);
        // scaled-units norm + 512 bias: scores positive => u32-monotone float bits
        if (lane == 0) cbn[row] = 8192.f * s + 512.f;
    } else {
        counts[(b - 6144) * 256 + threadIdx.x] = 0u;
        if (b == 6144 && threadIdx.x == 0) *ctr = 0u;
    }
}

// ---------------- MX-FP8 MFMA GEMM + fused running argmin ----------------
// Block: 128 rows x 2048 cols (16 chunks of 128). A-tile resident in LDS.
// score'[m][n] = (8192||e_n||^2+512) - 2*(x_m . 8192 e_n).
// Running u32 key per (i,r): score[31:11] | ch[10:7] | col[6:0] -> single
// v_min_u32 tracks (min score, ties -> lowest chunk, then lowest col).
__global__ __launch_bounds__(256) void vq_argmin_mfma(
        const unsigned char* __restrict__ xq,
        const unsigned char* __restrict__ cbq,
        const float* __restrict__ cbn,
        unsigned long long* __restrict__ partial) {
    __shared__ __align__(16) unsigned char As[2][128 * 128]; // kc-halves, [row][128B] swizzled
    __shared__ __align__(16) unsigned char Bs[128 * 128];
    __shared__ unsigned long long redk[2][128];

    const int tid = threadIdx.x;
    const int lane = tid & 63;
    const int w = tid >> 6;           // wave 0..3
    const int wm = w >> 1, wn = w & 1;
    const int l15 = lane & 15, q = lane >> 4;
    const int ns = blockIdx.x & (NSPLIT - 1);
    const int by = blockIdx.x / NSPLIT;
    const int m0 = by * 128;
    const int nbase = ns * (NUM_EMB / NSPLIT);

    const int sub = lane >> 3;        // row within 8-row segment
    const int sl  = lane & 7;         // 16B slot within 128B chunk-row

    // stage A once: 128 rows x 256B, two kc halves
    #pragma unroll
    for (int kc = 0; kc < 2; kc++)
        #pragma unroll
        for (int t = 0; t < 4; t++) {
            int seg = t * 4 + w;                   // wave-uniform
            int row = seg * 8 + sub;
            int blk = sl ^ (row & 7);              // XOR swizzle
            GL2LDS((const char*)xq + (size_t)(m0 + row) * 256 + kc * 128 + blk * 16,
                   (char*)As[kc] + seg * 1024);
        }

    unsigned int colb[4];
    #pragma unroll
    for (int j = 0; j < 4; j++) colb[j] = (unsigned)(wn * 64 + j * 16 + l15);

    unsigned int runk[4][4];
    #pragma unroll
    for (int i = 0; i < 4; i++)
        #pragma unroll
        for (int r = 0; r < 4; r++) runk[i][r] = 0xFFFFFFFFu;

    #pragma unroll 1
    for (int ch = 0; ch < CHUNKS; ch++) {
        const int n0c = nbase + ch * 128;
        const unsigned int chb = (unsigned)ch << 7;
        unsigned int cj[4];
        float bnj[4];
        #pragma unroll
        for (int j = 0; j < 4; j++) {
            cj[j] = chb | colb[j];
            bnj[j] = cbn[n0c + (int)colb[j]];
        }

        f32x4 acc[4][4];
        #pragma unroll
        for (int i = 0; i < 4; i++)
            #pragma unroll
            for (int j = 0; j < 4; j++) acc[i][j] = (f32x4)0.f;

        #pragma unroll
        for (int kc = 0; kc < 2; kc++) {
            __syncthreads();          // prev compute done before Bs overwrite
            #pragma unroll
            for (int t = 0; t < 4; t++) {
                int seg = t * 4 + w;
                int row = seg * 8 + sub;
                int blk = sl ^ (row & 7);
                GL2LDS((const char*)cbq + (size_t)(n0c + row) * 256 + kc * 128 + blk * 16,
                       (char*)Bs + seg * 1024);
            }
            __syncthreads();          // vmcnt(0) drain (covers A on first iter)

            i32x8 bfr[4];
            #pragma unroll
            for (int j = 0; j < 4; j++) {
                int row = wn * 64 + j * 16 + l15;
                int s0 = ((2 * q) ^ (row & 7)) * 16;
                int s1 = ((2 * q + 1) ^ (row & 7)) * 16;
                i32x4 lo = *(const i32x4*)(Bs + row * 128 + s0);
                i32x4 hi = *(const i32x4*)(Bs + row * 128 + s1);
                bfr[j] = __builtin_shufflevector(lo, hi, 0, 1, 2, 3, 4, 5, 6, 7);
            }
            #pragma unroll
            for (int i = 0; i < 4; i++) {
                int row = wm * 64 + i * 16 + l15;
                int s0 = ((2 * q) ^ (row & 7)) * 16;
                int s1 = ((2 * q + 1) ^ (row & 7)) * 16;
                i32x4 lo = *(const i32x4*)(As[kc] + row * 128 + s0);
                i32x4 hi = *(const i32x4*)(As[kc] + row * 128 + s1);
                i32x8 afr = __builtin_shufflevector(lo, hi, 0, 1, 2, 3, 4, 5, 6, 7);
                #pragma unroll
                for (int j = 0; j < 4; j++)
                    acc[i][j] = __builtin_amdgcn_mfma_scale_f32_16x16x128_f8f6f4(
                        afr, bfr[j], acc[i][j], 0, 0,    // fp8 / fp8
                        0, 127, 0, 127);                 // scales = 2^0
            }
        }

        // running-min update: fmaf + and_or pack + 4x v_min_u32 per (i,r)
        #pragma unroll
        for (int i = 0; i < 4; i++) {
            #pragma unroll
            for (int r = 0; r < 4; r++) {
                unsigned int k0 = (__float_as_uint(fmaf(-2.f, acc[i][0][r], bnj[0])) & 0xFFFFF800u) | cj[0];
                unsigned int k1 = (__float_as_uint(fmaf(-2.f, acc[i][1][r], bnj[1])) & 0xFFFFF800u) | cj[1];
                unsigned int k2 = (__float_as_uint(fmaf(-2.f, acc[i][2][r], bnj[2])) & 0xFFFFF800u) | cj[2];
                unsigned int k3 = (__float_as_uint(fmaf(-2.f, acc[i][3][r], bnj[3])) & 0xFFFFF800u) | cj[3];
                runk[i][r] = min(runk[i][r], min(min(k0, k1), min(k2, k3)));
            }
        }
    }

    // epilogue once per block: full u64 (score, global col) shuffle-min
    #pragma unroll
    for (int i = 0; i < 4; i++) {
        #pragma unroll
        for (int r = 0; r < 4; r++) {
            unsigned int rk = runk[i][r];
            unsigned int gcol = (unsigned)nbase + (rk & 0x7FFu);   // ch*128+col
            unsigned long long key =
                ((unsigned long long)(rk & 0xFFFFF800u) << 32) | gcol;
            #pragma unroll
            for (int off = 8; off >= 1; off >>= 1) {
                unsigned long long o = __shfl_xor(key, off, 16);
                if (o < key) key = o;
            }
            if (l15 == 0) redk[wn][wm * 64 + i * 16 + q * 4 + r] = key;
        }
    }
    __syncthreads();
    if (tid < 128) {
        unsigned long long k0 = redk[0][tid], k1 = redk[1][tid];
        partial[(size_t)ns * NROWS + m0 + tid] = k0 < k1 ? k0 : k1;   // coalesced
    }
}

// ---------------- fused: reduce partials -> gather/outputs/loss/counts -> last-block fin ----------------
__global__ __launch_bounds__(256) void vq_out(const float* __restrict__ x,
                                              const float* __restrict__ cb,
                                              const unsigned long long* __restrict__ partial,
                                              float* __restrict__ out,
                                              unsigned int* __restrict__ counts,
                                              double* __restrict__ loss_part,
                                              unsigned int* __restrict__ ctr,
                                              float* __restrict__ out_tail) {
    __shared__ float wred[4];
    __shared__ bool lastf;
    int wv   = threadIdx.x >> 6;
    int row  = blockIdx.x * 4 + wv;
    int lane = threadIdx.x & 63;
    unsigned long long k = 0xFFFFFFFFFFFFFFFFull;
    #pragma unroll
    for (int t = 0; t < NSPLIT; t++) {
        unsigned long long v = partial[(size_t)t * NROWS + row];
        if (v < k) k = v;
    }
    int id = (int)(unsigned int)(k & 0xffffffffu);   // wave-uniform
    float4 qv = ((const float4*)(cb + (size_t)id * DIM))[lane];
    float4 xv = ((const float4*)(x + (size_t)row * DIM))[lane];
    float dx = qv.x - xv.x, dy = qv.y - xv.y, dz = qv.z - xv.z, dw = qv.w - xv.w;
    float4 o;
    o.x = xv.x + dx; o.y = xv.y + dy; o.z = xv.z + dz; o.w = xv.w + dw;
    ((float4*)(out + (size_t)row * DIM))[lane] = o;
    float s = dx * dx + dy * dy + dz * dz + dw * dw;
    #pragma unroll
    for (int o2 = 32; o2 > 0; o2 >>= 1) s += __shfl_down(s, o2, 64);
    if (lane == 0) {
        wred[wv] = s;
        atomicAdd(&counts[id], 1u);
    }
    __syncthreads();
    if (threadIdx.x == 0) {
        loss_part[blockIdx.x] =
            (double)wred[0] + (double)wred[1] + (double)wred[2] + (double)wred[3];
        __threadfence();                              // release counts + loss_part
        lastf = (atomicAdd(ctr, 1u) == gridDim.x - 1);
    }
    __syncthreads();
    if (lastf) {
        __threadfence();                              // acquire others' writes
        __shared__ double sh[256];
        __shared__ double sl2[256];
        int tid = threadIdx.x;
        double h = 0.0;
        for (int c = tid; c < NUM_EMB; c += 256) {
            float p = (float)counts[c] / 32768.0f;
            h += (double)p * log((double)p + 1e-10);
        }
        double ls = 0.0;
        for (int b = tid; b < NROWS / 4; b += 256) ls += loss_part[b];
        sh[tid] = h;
        sl2[tid] = ls;
        __syncthreads();
        for (int o2 = 128; o2 > 0; o2 >>= 1) {
            if (tid < o2) { sh[tid] += sh[tid + o2]; sl2[tid] += sl2[tid + o2]; }
            __syncthreads();
        }
        if (tid == 0) {
            double mean = sl2[0] / (double)((size_t)NROWS * DIM);
            out_tail[0] = (float)(1.25 * mean);
            out_tail[1] = (float)exp(-sh[0]);
        }
    }
}

extern "C" void kernel_launch(void* const* d_in, const int* in_sizes, int n_in,
                              void* d_out, int out_size, void* d_ws, size_t ws_size,
                              hipStream_t stream) {
    const float* x  = (const float*)d_in[0];
    const float* cb = (const float*)d_in[1];
    char* ws = (char*)d_ws;
    unsigned int* ctr      = (unsigned int*)ws;                         // 4 B
    unsigned int* counts   = (unsigned int*)(ws + 256);                 // 32 KB
    float* cbn             = (float*)(ws + 33024);                      // 32 KB
    unsigned char* xq      = (unsigned char*)(ws + 65792);              // 8 MB fp8 x
    unsigned char* cbq     = (unsigned char*)(ws + 65792 + 8388608);    // 2 MB fp8 e*8192
    unsigned long long* pp = (unsigned long long*)(ws + 65792 + 8388608 + 2097152); // 1 MB
    double* loss_part      = (double*)(ws + 65792 + 8388608 + 2097152 + 16777216);  // 64 KB
    float* out = (float*)d_out;

    vq_prep       <<<6176, 256, 0, stream>>>(x, xq, cb, cbq, cbn, counts, ctr);
    vq_argmin_mfma<<<256 * NSPLIT, 256, 0, stream>>>(xq, cbq, cbn, pp);
    vq_out        <<<8192, 256, 0, stream>>>(x, cb, pp, out, counts, loss_part, ctr,
                                             out + (size_t)NROWS * DIM);
}

// Round 10
// 212.617 us; speedup vs baseline: 2.1922x; 2.1922x over previous
//
#include <hip/hip_runtime.h>
#include <cfloat>
#include <math.h>

#define NUM_EMB 8192
#define DIM 256
#define NROWS 32768
#define NSPLIT 4
#define CHUNKS 16   // 8192 / NSPLIT / 128

typedef float f32x4 __attribute__((ext_vector_type(4)));
typedef int   i32x4 __attribute__((ext_vector_type(4)));
typedef int   i32x8 __attribute__((ext_vector_type(8)));

#define GL2LDS(g, l) __builtin_amdgcn_global_load_lds( \
    (const __attribute__((address_space(1))) void*)(g), \
    (__attribute__((address_space(3))) void*)(l), 16, 0, 0)

// ---------------- prep: x -> fp8 ; codebook -> fp8(e*8192) + biased norms ; zero counts ----------------
__global__ __launch_bounds__(256) void vq_prep(const float* __restrict__ x,
                                               unsigned char* __restrict__ xq,
                                               const float* __restrict__ cb,
                                               unsigned char* __restrict__ cbq,
                                               float* __restrict__ cbn,
                                               unsigned int* __restrict__ counts) {
    int b = blockIdx.x;
    if (b < 4096) {
        int i = b * 256 + threadIdx.x;               // over 8-float groups
        float4 v0 = ((const float4*)x)[2 * i];
        float4 v1 = ((const float4*)x)[2 * i + 1];
        int p0 = __builtin_amdgcn_cvt_pk_fp8_f32(v0.x, v0.y, 0, false);
        p0     = __builtin_amdgcn_cvt_pk_fp8_f32(v0.z, v0.w, p0, true);
        int p1 = __builtin_amdgcn_cvt_pk_fp8_f32(v1.x, v1.y, 0, false);
        p1     = __builtin_amdgcn_cvt_pk_fp8_f32(v1.z, v1.w, p1, true);
        ((int2*)xq)[i] = make_int2(p0, p1);
    } else if (b < 6144) {
        int row  = (b - 4096) * 4 + (threadIdx.x >> 6);
        int lane = threadIdx.x & 63;
        float4 v = ((const float4*)(cb + (size_t)row * DIM))[lane];
        // store e*8192 in fp8 (range (-1,1)); scale folds out of the argmin
        int p = __builtin_amdgcn_cvt_pk_fp8_f32(v.x * 8192.f, v.y * 8192.f, 0, false);
        p     = __builtin_amdgcn_cvt_pk_fp8_f32(v.z * 8192.f, v.w * 8192.f, p, true);
        ((int*)cbq)[row * 64 + lane] = p;
        float s = v.x * v.x + v.y * v.y + v.z * v.z + v.w * v.w;
        #pragma unroll
        for (int off = 32; off > 0; off >>= 1) s += __shfl_down(s, off, 64);
        // scaled-units norm + 512 bias: scores positive => u32-monotone float bits
        if (lane == 0) cbn[row] = 8192.f * s + 512.f;
    } else {
        counts[(b - 6144) * 256 + threadIdx.x] = 0u;
    }
}

// ---------------- MX-FP8 MFMA GEMM + fused running argmin ----------------
// Block: 128 rows x 2048 cols (16 chunks of 128). A-tile resident in LDS.
// score'[m][n] = (8192||e_n||^2+512) - 2*(x_m . 8192 e_n).
// Running u32 key per (i,r): score[31:11] | ch[10:7] | col[6:0] -> single
// v_min_u32 tracks (min score, ties -> lowest chunk, then lowest col).
__global__ __launch_bounds__(256) void vq_argmin_mfma(
        const unsigned char* __restrict__ xq,
        const unsigned char* __restrict__ cbq,
        const float* __restrict__ cbn,
        unsigned long long* __restrict__ partial) {
    __shared__ __align__(16) unsigned char As[2][128 * 128]; // kc-halves, [row][128B] swizzled
    __shared__ __align__(16) unsigned char Bs[128 * 128];
    __shared__ unsigned long long redk[2][128];

    const int tid = threadIdx.x;
    const int lane = tid & 63;
    const int w = tid >> 6;           // wave 0..3
    const int wm = w >> 1, wn = w & 1;
    const int l15 = lane & 15, q = lane >> 4;
    const int ns = blockIdx.x & (NSPLIT - 1);
    const int by = blockIdx.x / NSPLIT;
    const int m0 = by * 128;
    const int nbase = ns * (NUM_EMB / NSPLIT);

    const int sub = lane >> 3;        // row within 8-row segment
    const int sl  = lane & 7;         // 16B slot within 128B chunk-row

    // stage A once: 128 rows x 256B, two kc halves
    #pragma unroll
    for (int kc = 0; kc < 2; kc++)
        #pragma unroll
        for (int t = 0; t < 4; t++) {
            int seg = t * 4 + w;                   // wave-uniform
            int row = seg * 8 + sub;
            int blk = sl ^ (row & 7);              // XOR swizzle
            GL2LDS((const char*)xq + (size_t)(m0 + row) * 256 + kc * 128 + blk * 16,
                   (char*)As[kc] + seg * 1024);
        }

    unsigned int colb[4];
    #pragma unroll
    for (int j = 0; j < 4; j++) colb[j] = (unsigned)(wn * 64 + j * 16 + l15);

    unsigned int runk[4][4];
    #pragma unroll
    for (int i = 0; i < 4; i++)
        #pragma unroll
        for (int r = 0; r < 4; r++) runk[i][r] = 0xFFFFFFFFu;

    #pragma unroll 1
    for (int ch = 0; ch < CHUNKS; ch++) {
        const int n0c = nbase + ch * 128;
        const unsigned int chb = (unsigned)ch << 7;
        unsigned int cj[4];
        float bnj[4];
        #pragma unroll
        for (int j = 0; j < 4; j++) {
            cj[j] = chb | colb[j];
            bnj[j] = cbn[n0c + (int)colb[j]];
        }

        f32x4 acc[4][4];
        #pragma unroll
        for (int i = 0; i < 4; i++)
            #pragma unroll
            for (int j = 0; j < 4; j++) acc[i][j] = (f32x4)0.f;

        #pragma unroll
        for (int kc = 0; kc < 2; kc++) {
            __syncthreads();          // prev compute done before Bs overwrite
            #pragma unroll
            for (int t = 0; t < 4; t++) {
                int seg = t * 4 + w;
                int row = seg * 8 + sub;
                int blk = sl ^ (row & 7);
                GL2LDS((const char*)cbq + (size_t)(n0c + row) * 256 + kc * 128 + blk * 16,
                       (char*)Bs + seg * 1024);
            }
            __syncthreads();          // vmcnt(0) drain (covers A on first iter)

            i32x8 bfr[4];
            #pragma unroll
            for (int j = 0; j < 4; j++) {
                int row = wn * 64 + j * 16 + l15;
                int s0 = ((2 * q) ^ (row & 7)) * 16;
                int s1 = ((2 * q + 1) ^ (row & 7)) * 16;
                i32x4 lo = *(const i32x4*)(Bs + row * 128 + s0);
                i32x4 hi = *(const i32x4*)(Bs + row * 128 + s1);
                bfr[j] = __builtin_shufflevector(lo, hi, 0, 1, 2, 3, 4, 5, 6, 7);
            }
            #pragma unroll
            for (int i = 0; i < 4; i++) {
                int row = wm * 64 + i * 16 + l15;
                int s0 = ((2 * q) ^ (row & 7)) * 16;
                int s1 = ((2 * q + 1) ^ (row & 7)) * 16;
                i32x4 lo = *(const i32x4*)(As[kc] + row * 128 + s0);
                i32x4 hi = *(const i32x4*)(As[kc] + row * 128 + s1);
                i32x8 afr = __builtin_shufflevector(lo, hi, 0, 1, 2, 3, 4, 5, 6, 7);
                #pragma unroll
                for (int j = 0; j < 4; j++)
                    acc[i][j] = __builtin_amdgcn_mfma_scale_f32_16x16x128_f8f6f4(
                        afr, bfr[j], acc[i][j], 0, 0,    // fp8 / fp8
                        0, 127, 0, 127);                 // scales = 2^0
            }
        }

        // running-min update: fmaf + and_or pack + 4x v_min_u32 per (i,r)
        #pragma unroll
        for (int i = 0; i < 4; i++) {
            #pragma unroll
            for (int r = 0; r < 4; r++) {
                unsigned int k0 = (__float_as_uint(fmaf(-2.f, acc[i][0][r], bnj[0])) & 0xFFFFF800u) | cj[0];
                unsigned int k1 = (__float_as_uint(fmaf(-2.f, acc[i][1][r], bnj[1])) & 0xFFFFF800u) | cj[1];
                unsigned int k2 = (__float_as_uint(fmaf(-2.f, acc[i][2][r], bnj[2])) & 0xFFFFF800u) | cj[2];
                unsigned int k3 = (__float_as_uint(fmaf(-2.f, acc[i][3][r], bnj[3])) & 0xFFFFF800u) | cj[3];
                runk[i][r] = min(runk[i][r], min(min(k0, k1), min(k2, k3)));
            }
        }
    }

    // epilogue once per block: full u64 (score, global col) shuffle-min
    #pragma unroll
    for (int i = 0; i < 4; i++) {
        #pragma unroll
        for (int r = 0; r < 4; r++) {
            unsigned int rk = runk[i][r];
            unsigned int gcol = (unsigned)nbase + (rk & 0x7FFu);   // ch*128+col
            unsigned long long key =
                ((unsigned long long)(rk & 0xFFFFF800u) << 32) | gcol;
            #pragma unroll
            for (int off = 8; off >= 1; off >>= 1) {
                unsigned long long o = __shfl_xor(key, off, 16);
                if (o < key) key = o;
            }
            if (l15 == 0) redk[wn][wm * 64 + i * 16 + q * 4 + r] = key;
        }
    }
    __syncthreads();
    if (tid < 128) {
        unsigned long long k0 = redk[0][tid], k1 = redk[1][tid];
        partial[(size_t)ns * NROWS + m0 + tid] = k0 < k1 ? k0 : k1;   // coalesced
    }
}

// ---------------- fused: reduce partials -> gather + outputs + loss + counts ----------------
__global__ __launch_bounds__(256) void vq_out(const float* __restrict__ x,
                                              const float* __restrict__ cb,
                                              const unsigned long long* __restrict__ partial,
                                              float* __restrict__ out,
                                              unsigned int* __restrict__ counts,
                                              double* __restrict__ loss_part) {
    __shared__ float wred[4];
    int wv   = threadIdx.x >> 6;
    int row  = blockIdx.x * 4 + wv;
    int lane = threadIdx.x & 63;
    unsigned long long k = 0xFFFFFFFFFFFFFFFFull;
    #pragma unroll
    for (int t = 0; t < NSPLIT; t++) {
        unsigned long long v = partial[(size_t)t * NROWS + row];
        if (v < k) k = v;
    }
    int id = (int)(unsigned int)(k & 0xffffffffu);   // wave-uniform
    float4 qv = ((const float4*)(cb + (size_t)id * DIM))[lane];
    float4 xv = ((const float4*)(x + (size_t)row * DIM))[lane];
    float dx = qv.x - xv.x, dy = qv.y - xv.y, dz = qv.z - xv.z, dw = qv.w - xv.w;
    float4 o;
    o.x = xv.x + dx; o.y = xv.y + dy; o.z = xv.z + dz; o.w = xv.w + dw;
    ((float4*)(out + (size_t)row * DIM))[lane] = o;
    float s = dx * dx + dy * dy + dz * dz + dw * dw;
    #pragma unroll
    for (int o2 = 32; o2 > 0; o2 >>= 1) s += __shfl_down(s, o2, 64);
    if (lane == 0) {
        wred[wv] = s;
        atomicAdd(&counts[id], 1u);
    }
    __syncthreads();
    if (threadIdx.x == 0) {
        loss_part[blockIdx.x] =
            (double)wred[0] + (double)wred[1] + (double)wred[2] + (double)wred[3];
    }
}

// ---------------- finalize loss + perplexity ----------------
__global__ __launch_bounds__(256) void vq_fin(const unsigned int* __restrict__ counts,
                                              const double* __restrict__ loss_part,
                                              float* __restrict__ out_tail) {
    __shared__ double sh[256];
    __shared__ double sl[256];
    int tid = threadIdx.x;
    double h = 0.0;
    for (int k = tid; k < NUM_EMB; k += 256) {
        float p = (float)counts[k] / 32768.0f;
        h += (double)p * log((double)p + 1e-10);
    }
    double ls = 0.0;
    for (int b = tid; b < NROWS / 4; b += 256) ls += loss_part[b];
    sh[tid] = h;
    sl[tid] = ls;
    __syncthreads();
    for (int o = 128; o > 0; o >>= 1) {
        if (tid < o) { sh[tid] += sh[tid + o]; sl[tid] += sl[tid + o]; }
        __syncthreads();
    }
    if (tid == 0) {
        double mean = sl[0] / (double)((size_t)NROWS * DIM);
        out_tail[0] = (float)(1.25 * mean);
        out_tail[1] = (float)exp(-sh[0]);
    }
}

extern "C" void kernel_launch(void* const* d_in, const int* in_sizes, int n_in,
                              void* d_out, int out_size, void* d_ws, size_t ws_size,
                              hipStream_t stream) {
    const float* x  = (const float*)d_in[0];
    const float* cb = (const float*)d_in[1];
    char* ws = (char*)d_ws;
    unsigned int* counts   = (unsigned int*)(ws + 256);                 // 32 KB
    float* cbn             = (float*)(ws + 33024);                      // 32 KB
    unsigned char* xq      = (unsigned char*)(ws + 65792);              // 8 MB fp8 x
    unsigned char* cbq     = (unsigned char*)(ws + 65792 + 8388608);    // 2 MB fp8 e*8192
    unsigned long long* pp = (unsigned long long*)(ws + 65792 + 8388608 + 2097152); // 1 MB
    double* loss_part      = (double*)(ws + 65792 + 8388608 + 2097152 + 16777216);  // 64 KB
    float* out = (float*)d_out;

    vq_prep       <<<6176, 256, 0, stream>>>(x, xq, cb, cbq, cbn, counts);
    vq_argmin_mfma<<<256 * NSPLIT, 256, 0, stream>>>(xq, cbq, cbn, pp);
    vq_out        <<<8192, 256, 0, stream>>>(x, cb, pp, out, counts, loss_part);
    vq_fin        <<<1, 256, 0, stream>>>(counts, loss_part, out + (size_t)NROWS * DIM);
}

// Round 11
// 211.567 us; speedup vs baseline: 2.2031x; 1.0050x over previous
//
#include <hip/hip_runtime.h>
#include <cfloat>
#include <math.h>

#define NUM_EMB 8192
#define DIM 256
#define NROWS 32768
#define NSPLIT 4
#define CHUNKS 16   // (8192 / NSPLIT) / 128

typedef float f32x4 __attribute__((ext_vector_type(4)));
typedef int   i32x4 __attribute__((ext_vector_type(4)));
typedef int   i32x8 __attribute__((ext_vector_type(8)));

#define GL2LDS(g, l) __builtin_amdgcn_global_load_lds( \
    (const __attribute__((address_space(1))) void*)(g), \
    (__attribute__((address_space(3))) void*)(l), 16, 0, 0)

// ---------------- prep: x -> fp8 ; codebook -> fp8(e*8192) + biased norms ; zero counts ----------------
__global__ __launch_bounds__(256) void vq_prep(const float* __restrict__ x,
                                               unsigned char* __restrict__ xq,
                                               const float* __restrict__ cb,
                                               unsigned char* __restrict__ cbq,
                                               float* __restrict__ cbn,
                                               unsigned int* __restrict__ counts) {
    int b = blockIdx.x;
    if (b < 4096) {
        int i = b * 256 + threadIdx.x;               // over 8-float groups
        float4 v0 = ((const float4*)x)[2 * i];
        float4 v1 = ((const float4*)x)[2 * i + 1];
        int p0 = __builtin_amdgcn_cvt_pk_fp8_f32(v0.x, v0.y, 0, false);
        p0     = __builtin_amdgcn_cvt_pk_fp8_f32(v0.z, v0.w, p0, true);
        int p1 = __builtin_amdgcn_cvt_pk_fp8_f32(v1.x, v1.y, 0, false);
        p1     = __builtin_amdgcn_cvt_pk_fp8_f32(v1.z, v1.w, p1, true);
        ((int2*)xq)[i] = make_int2(p0, p1);
    } else if (b < 6144) {
        int row  = (b - 4096) * 4 + (threadIdx.x >> 6);
        int lane = threadIdx.x & 63;
        float4 v = ((const float4*)(cb + (size_t)row * DIM))[lane];
        // store e*8192 in fp8 (range (-1,1)); scale folds out of the argmin
        int p = __builtin_amdgcn_cvt_pk_fp8_f32(v.x * 8192.f, v.y * 8192.f, 0, false);
        p     = __builtin_amdgcn_cvt_pk_fp8_f32(v.z * 8192.f, v.w * 8192.f, p, true);
        ((int*)cbq)[row * 64 + lane] = p;
        float s = v.x * v.x + v.y * v.y + v.z * v.z + v.w * v.w;
        #pragma unroll
        for (int off = 32; off > 0; off >>= 1) s += __shfl_down(s, off, 64);
        // scaled-units norm + 512 bias: scores positive => u32-monotone float bits
        if (lane == 0) cbn[row] = 8192.f * s + 512.f;
    } else {
        counts[(b - 6144) * 256 + threadIdx.x] = 0u;
    }
}

// ---------------- MX-FP8 MFMA GEMM + fused running argmin ----------------
// Block: 64 rows x 2048 cols (16 chunks of 128). A-fragments in REGISTERS
// (loaded once per block from xq); B streamed through one 32KB LDS buffer.
// score'[m][n] = (8192||e_n||^2+512) - 2*(x_m . 8192 e_n).
// Running u32 key per (i,r): score[31:11] | ch[10:7] | col[6:0] -> single
// v_min_u32 tracks (min score, ties -> lowest chunk, then lowest col).
__global__ __launch_bounds__(256, 4) void vq_argmin_mfma(
        const unsigned char* __restrict__ xq,
        const unsigned char* __restrict__ cbq,
        const float* __restrict__ cbn,
        unsigned long long* __restrict__ partial) {
    __shared__ __align__(16) unsigned char Bs[128 * 256];  // [row][256B], blocks swizzled per 128B half
    __shared__ unsigned long long redk[2][64];

    const int tid = threadIdx.x;
    const int lane = tid & 63;
    const int w = tid >> 6;           // wave 0..3
    const int wm = w >> 1, wn = w & 1;
    const int l15 = lane & 15, q = lane >> 4;
    const int ns = blockIdx.x & (NSPLIT - 1);
    const int by = blockIdx.x / NSPLIT;
    const int m0 = by * 64;
    const int nbase = ns * (NUM_EMB / NSPLIT);

    // A fragments in registers: [kc][i], 32B/lane each = k-bytes kc*128+q*32..+31
    i32x8 afr[2][2];
    #pragma unroll
    for (int kc = 0; kc < 2; kc++)
        #pragma unroll
        for (int i = 0; i < 2; i++) {
            const unsigned char* p =
                xq + (size_t)(m0 + wm * 32 + i * 16 + l15) * 256 + kc * 128 + q * 32;
            i32x4 lo = *(const i32x4*)p;
            i32x4 hi = *(const i32x4*)(p + 16);
            afr[kc][i] = __builtin_shufflevector(lo, hi, 0, 1, 2, 3, 4, 5, 6, 7);
        }

    unsigned int colb[4];
    #pragma unroll
    for (int j = 0; j < 4; j++) colb[j] = (unsigned)(wn * 64 + j * 16 + l15);

    unsigned int runk[2][4];
    #pragma unroll
    for (int i = 0; i < 2; i++)
        #pragma unroll
        for (int r = 0; r < 4; r++) runk[i][r] = 0xFFFFFFFFu;

    // staging coords (wave-lane -> row/slot within a 1KB segment of 4 rows)
    const int sr = lane >> 4;         // row within segment 0..3
    const int sv = lane & 15;         // 16B slot within row: kc = sv>>3, blk = sv&7

    #pragma unroll 1
    for (int ch = 0; ch < CHUNKS; ch++) {
        const int n0c = nbase + ch * 128;
        const unsigned int chb = (unsigned)ch << 7;
        unsigned int cj[4];
        float bnj[4];
        #pragma unroll
        for (int j = 0; j < 4; j++) {
            cj[j] = chb | colb[j];
            bnj[j] = cbn[n0c + (int)colb[j]];
        }

        f32x4 acc[2][4];
        #pragma unroll
        for (int i = 0; i < 2; i++)
            #pragma unroll
            for (int j = 0; j < 4; j++) acc[i][j] = (f32x4)0.f;

        __syncthreads();              // prev chunk's compute done before Bs overwrite
        #pragma unroll
        for (int t = 0; t < 8; t++) {
            int s = t * 4 + w;                         // segment 0..31, wave-uniform
            int row = s * 4 + sr;                      // chunk-local codebook row
            int kcs = sv >> 3, blk = sv & 7;
            GL2LDS(cbq + (size_t)(n0c + row) * 256 + kcs * 128 + ((blk ^ (row & 7)) * 16),
                   (char*)Bs + s * 1024);
        }
        __syncthreads();              // vmcnt(0) drain: Bs ready

        #pragma unroll
        for (int kc = 0; kc < 2; kc++) {
            #pragma unroll
            for (int j = 0; j < 4; j++) {
                int row = wn * 64 + j * 16 + l15;
                int base = row * 256 + kc * 128;
                int s0 = ((2 * q) ^ (row & 7)) * 16;
                int s1 = ((2 * q + 1) ^ (row & 7)) * 16;
                i32x4 lo = *(const i32x4*)(Bs + base + s0);
                i32x4 hi = *(const i32x4*)(Bs + base + s1);
                i32x8 bfr = __builtin_shufflevector(lo, hi, 0, 1, 2, 3, 4, 5, 6, 7);
                acc[0][j] = __builtin_amdgcn_mfma_scale_f32_16x16x128_f8f6f4(
                    afr[kc][0], bfr, acc[0][j], 0, 0, 0, 127, 0, 127);
                acc[1][j] = __builtin_amdgcn_mfma_scale_f32_16x16x128_f8f6f4(
                    afr[kc][1], bfr, acc[1][j], 0, 0, 0, 127, 0, 127);
            }
        }

        // running-min update: fmaf + and_or pack + 4x v_min_u32 per (i,r)
        #pragma unroll
        for (int i = 0; i < 2; i++) {
            #pragma unroll
            for (int r = 0; r < 4; r++) {
                unsigned int k0 = (__float_as_uint(fmaf(-2.f, acc[i][0][r], bnj[0])) & 0xFFFFF800u) | cj[0];
                unsigned int k1 = (__float_as_uint(fmaf(-2.f, acc[i][1][r], bnj[1])) & 0xFFFFF800u) | cj[1];
                unsigned int k2 = (__float_as_uint(fmaf(-2.f, acc[i][2][r], bnj[2])) & 0xFFFFF800u) | cj[2];
                unsigned int k3 = (__float_as_uint(fmaf(-2.f, acc[i][3][r], bnj[3])) & 0xFFFFF800u) | cj[3];
                runk[i][r] = min(runk[i][r], min(min(k0, k1), min(k2, k3)));
            }
        }
    }

    // epilogue once per block: full u64 (score, global col) shuffle-min
    #pragma unroll
    for (int i = 0; i < 2; i++) {
        #pragma unroll
        for (int r = 0; r < 4; r++) {
            unsigned int rk = runk[i][r];
            unsigned int gcol = (unsigned)nbase + (rk & 0x7FFu);   // ch*128+col
            unsigned long long key =
                ((unsigned long long)(rk & 0xFFFFF800u) << 32) | gcol;
            #pragma unroll
            for (int off = 8; off >= 1; off >>= 1) {
                unsigned long long o = __shfl_xor(key, off, 16);
                if (o < key) key = o;
            }
            if (l15 == 0) redk[wn][wm * 32 + i * 16 + q * 4 + r] = key;
        }
    }
    __syncthreads();
    if (tid < 64) {
        unsigned long long k0 = redk[0][tid], k1 = redk[1][tid];
        partial[(size_t)ns * NROWS + m0 + tid] = k0 < k1 ? k0 : k1;   // coalesced
    }
}

// ---------------- fused: reduce partials -> gather + outputs + loss + counts ----------------
__global__ __launch_bounds__(256) void vq_out(const float* __restrict__ x,
                                              const float* __restrict__ cb,
                                              const unsigned long long* __restrict__ partial,
                                              float* __restrict__ out,
                                              unsigned int* __restrict__ counts,
                                              double* __restrict__ loss_part) {
    __shared__ float wred[4];
    int wv   = threadIdx.x >> 6;
    int row  = blockIdx.x * 4 + wv;
    int lane = threadIdx.x & 63;
    unsigned long long k = 0xFFFFFFFFFFFFFFFFull;
    #pragma unroll
    for (int t = 0; t < NSPLIT; t++) {
        unsigned long long v = partial[(size_t)t * NROWS + row];
        if (v < k) k = v;
    }
    int id = (int)(unsigned int)(k & 0xffffffffu);   // wave-uniform
    float4 qv = ((const float4*)(cb + (size_t)id * DIM))[lane];
    float4 xv = ((const float4*)(x + (size_t)row * DIM))[lane];
    float dx = qv.x - xv.x, dy = qv.y - xv.y, dz = qv.z - xv.z, dw = qv.w - xv.w;
    float4 o;
    o.x = xv.x + dx; o.y = xv.y + dy; o.z = xv.z + dz; o.w = xv.w + dw;
    ((float4*)(out + (size_t)row * DIM))[lane] = o;
    float s = dx * dx + dy * dy + dz * dz + dw * dw;
    #pragma unroll
    for (int o2 = 32; o2 > 0; o2 >>= 1) s += __shfl_down(s, o2, 64);
    if (lane == 0) {
        wred[wv] = s;
        atomicAdd(&counts[id], 1u);
    }
    __syncthreads();
    if (threadIdx.x == 0) {
        loss_part[blockIdx.x] =
            (double)wred[0] + (double)wred[1] + (double)wred[2] + (double)wred[3];
    }
}

// ---------------- finalize loss + perplexity ----------------
__global__ __launch_bounds__(256) void vq_fin(const unsigned int* __restrict__ counts,
                                              const double* __restrict__ loss_part,
                                              float* __restrict__ out_tail) {
    __shared__ double sh[256];
    __shared__ double sl[256];
    int tid = threadIdx.x;
    double h = 0.0;
    for (int k = tid; k < NUM_EMB; k += 256) {
        float p = (float)counts[k] / 32768.0f;
        h += (double)p * log((double)p + 1e-10);
    }
    double ls = 0.0;
    for (int b = tid; b < NROWS / 4; b += 256) ls += loss_part[b];
    sh[tid] = h;
    sl[tid] = ls;
    __syncthreads();
    for (int o = 128; o > 0; o >>= 1) {
        if (tid < o) { sh[tid] += sh[tid + o]; sl[tid] += sl[tid + o]; }
        __syncthreads();
    }
    if (tid == 0) {
        double mean = sl[0] / (double)((size_t)NROWS * DIM);
        out_tail[0] = (float)(1.25 * mean);
        out_tail[1] = (float)exp(-sh[0]);
    }
}

extern "C" void kernel_launch(void* const* d_in, const int* in_sizes, int n_in,
                              void* d_out, int out_size, void* d_ws, size_t ws_size,
                              hipStream_t stream) {
    const float* x  = (const float*)d_in[0];
    const float* cb = (const float*)d_in[1];
    char* ws = (char*)d_ws;
    unsigned int* counts   = (unsigned int*)(ws + 256);                 // 32 KB
    float* cbn             = (float*)(ws + 33024);                      // 32 KB
    unsigned char* xq      = (unsigned char*)(ws + 65792);              // 8 MB fp8 x
    unsigned char* cbq     = (unsigned char*)(ws + 65792 + 8388608);    // 2 MB fp8 e*8192
    unsigned long long* pp = (unsigned long long*)(ws + 65792 + 8388608 + 2097152); // 1 MB
    double* loss_part      = (double*)(ws + 65792 + 8388608 + 2097152 + 16777216);  // 64 KB
    float* out = (float*)d_out;

    vq_prep       <<<6176, 256, 0, stream>>>(x, xq, cb, cbq, cbn, counts);
    vq_argmin_mfma<<<512 * NSPLIT, 256, 0, stream>>>(xq, cbq, cbn, pp);
    vq_out        <<<8192, 256, 0, stream>>>(x, cb, pp, out, counts, loss_part);
    vq_fin        <<<1, 256, 0, stream>>>(counts, loss_part, out + (size_t)NROWS * DIM);
}